// Round 9
// baseline (393.493 us; speedup 1.0000x reference)
//
#include <hip/hip_runtime.h>
#include <hip/hip_bf16.h>

// B=64, T=256, D=128, H=8, E=128, H*E=1024.
// Algebra (verified R1-R8): with xw[b]=Ws^T x[b], Sw=sum(Ws):
//   Kw[b,he]   = xw[b] @ Wk[:,he] + Sw*bk[he]
//   wqk[b,h,d] = SCALE * sum_e Wq[d,h*128+e]*Kw[b,h,e]   (bq, bs drop)
//   beta[b,h,t]= softmax_t( x[b,t] . wqk[b,h] )
//   xb[b,h,d]  = sum_t beta[b,h,t]*x[b,t,d]
//   res[b,he]  = xb[b,h] @ Wv[:,he] + bv[he]
//   out[b,d']  = res[b] @ Wo[:,d'] + bo[d']
//
// R9: single kernel, 256 blocks (1/CU, all co-resident -> flag pipeline is
// deadlock-free). Roles:
//   id   0..127 : b-half blocks (b=id>>1, hf=id&1): stage x-half in LDS ONCE;
//                 xw-half -> scores -> softmax (halves exchange m/s) -> xb-half.
//   id 128..159 : Kw blocks  (he-32 chunk in regs, loop all 64 b)
//   id 160..191 : wqk blocks (h, d-quarter slice in regs)
//   id 192..223 : res blocks (he-32 chunk of Wv in regs)
//   id 224..255 : out blocks (he-32 chunk of Wo in regs, atomicAdd to out)
// Cross-block data via d_ws + release/acquire flags. ws reads are laundered
// through a VGPR so they stay VMEM (L1 invalidated by __threadfence; avoids
// the stale scalar-cache s_load path). This cuts per-CU load traffic from
// ~768 KB (R8's 19x amplification = the measured 43us floor) to ~80 KB.

#define SCALE 0.08838834764831845f
#define MAGIC 0x13579BDFu

// ---- ws float offsets ----
#define XWP0  0        // [b][128]  hf0 xw partial
#define XWF   8192     // [b][128]  full xw
#define KWQ   16384    // [b][1024]
#define WQKQ  81920    // [b][1024] pre-scaled
#define MPUB  147456   // [b][hf][8]
#define SPUB  148480   // [b][hf][8]
#define XBP0  149504   // [b][1024] hf0 xb partial
#define XBF   215040   // [b][1024] full xb
#define RESQ  280576   // [b][1024]
#define FLGO  346112   // uint flags
#define F_XW0(b)   (b)
#define F_XWF(b)   (64+(b))
#define F_KW(c)    (128+(c))
#define F_WQ(g)    (160+(g))
#define F_M(b,hf)  (192+2*(b)+(hf))
#define F_S(b,hf)  (320+2*(b)+(hf))
#define F_XB0(b)   (448+(b))
#define F_XBF(b)   (512+(b))
#define F_RS(c)    (576+(c))

__device__ __forceinline__ const float* vl(const float* p) {
    unsigned long long u = (unsigned long long)p;
    asm("" : "+v"(u));                 // force VMEM path (divergent-assumed)
    return (const float*)u;
}
__device__ __forceinline__ void sig(unsigned* f) {
    __hip_atomic_store(f, MAGIC, __ATOMIC_RELEASE, __HIP_MEMORY_SCOPE_AGENT);
}
__device__ __forceinline__ void wt(unsigned* f) {
    while (__hip_atomic_load(f, __ATOMIC_ACQUIRE, __HIP_MEMORY_SCOPE_AGENT) != MAGIC) {
        __builtin_amdgcn_s_sleep(2);
    }
}

__global__ __launch_bounds__(256, 1)
void ta_pipe(const float* __restrict__ x,  const float* __restrict__ Wq,
             const float* __restrict__ Wk, const float* __restrict__ bk,
             const float* __restrict__ Wv, const float* __restrict__ bv,
             const float* __restrict__ Wsv,
             const float* __restrict__ Wo, const float* __restrict__ bov,
             float* __restrict__ ws, float* __restrict__ out)
{
    __shared__ float sm[20224];
    unsigned* flg = (unsigned*)(ws + FLGO);
    const int tid = threadIdx.x;
    const int id  = blockIdx.x;

    if (id < 128) {
        // ---------------- b-half ----------------
        const int b = id >> 1, hf = id & 1;
        float* xS  = sm;            // [128][132]
        float* pA  = sm + 16896;    // [8][128]
        float* scr = sm + 17920;    // [128][17]; holds Ws-half during staging
        const float* xb0 = x + (size_t)b * 32768 + (size_t)hf * 128 * 128;

        if (tid < 32) *(float4*)(scr + 4 * tid) = *(const float4*)(Wsv + hf * 128 + 4 * tid);
        __syncthreads();

        const int q = tid & 31, tc = tid >> 5;
        {   // stage x-half + xw-half partial
            float4 aw = {0.f, 0.f, 0.f, 0.f};
            #pragma unroll
            for (int j = 0; j < 16; ++j) {
                const int t = tc * 16 + j;
                const float4 v = *(const float4*)(xb0 + (size_t)t * 128 + 4 * q);
                *(float4*)(xS + t * 132 + 4 * q) = v;
                const float s = scr[t];
                aw.x += s * v.x; aw.y += s * v.y; aw.z += s * v.z; aw.w += s * v.w;
            }
            *(float4*)(pA + tc * 128 + 4 * q) = aw;
        }
        __syncthreads();
        float xwh = 0.f;
        if (tid < 128) {
            #pragma unroll
            for (int g = 0; g < 8; ++g) xwh += pA[g * 128 + tid];
        }
        if (hf == 0) {
            if (tid < 128) ws[XWP0 + b * 128 + tid] = xwh;
            __threadfence(); __syncthreads();
            if (tid == 0) sig(&flg[F_XW0(b)]);
        } else {
            if (tid == 0) wt(&flg[F_XW0(b)]);
            __syncthreads(); __threadfence();
            if (tid < 128) ws[XWF + b * 128 + tid] = xwh + vl(ws + XWP0 + b * 128)[tid];
            __threadfence(); __syncthreads();
            if (tid == 0) sig(&flg[F_XWF(b)]);
        }

        if (tid < 32) wt(&flg[F_WQ(tid)]);
        __syncthreads(); __threadfence();

        // scores for our 128 t's (x from LDS, wqk broadcast VMEM loads)
        const int tt = tid & 127, dp = tid >> 7;
        {
            float acc[8] = {0.f,0.f,0.f,0.f,0.f,0.f,0.f,0.f};
            const float* wqp = vl(ws + WQKQ + (size_t)b * 1024 + dp * 64);
            #pragma unroll 4
            for (int c2 = 0; c2 < 16; ++c2) {
                const float4 xv = *(const float4*)(xS + tt * 132 + dp * 64 + 4 * c2);
                #pragma unroll
                for (int h = 0; h < 8; ++h) {
                    const float4 qv = *(const float4*)(wqp + h * 128 + 4 * c2);
                    acc[h] += xv.x*qv.x + xv.y*qv.y + xv.z*qv.z + xv.w*qv.w;
                }
            }
            #pragma unroll
            for (int h = 0; h < 8; ++h) scr[tt * 17 + dp * 8 + h] = acc[h];
        }
        __syncthreads();

        // softmax: half-local reduce, exchange m/s with peer half
        const int hh = tid >> 5, qq = tid & 31;
        float st[4], ev[4];
        float m = -3.4e38f;
        #pragma unroll
        for (int i = 0; i < 4; ++i) {
            const int t = 4 * qq + i;
            st[i] = scr[t * 17 + hh] + scr[t * 17 + 8 + hh];
            m = fmaxf(m, st[i]);
        }
        #pragma unroll
        for (int off = 16; off; off >>= 1) m = fmaxf(m, __shfl_xor(m, off, 64));
        if (qq == 0) ws[MPUB + b * 16 + hf * 8 + hh] = m;
        __threadfence(); __syncthreads();
        if (tid == 0) { sig(&flg[F_M(b, hf)]); wt(&flg[F_M(b, 1 - hf)]); }
        __syncthreads(); __threadfence();
        const float M = fmaxf(m, vl(ws + MPUB + b * 16 + (1 - hf) * 8)[hh]);
        float es = 0.f;
        #pragma unroll
        for (int i = 0; i < 4; ++i) { ev[i] = __expf(st[i] - M); es += ev[i]; }
        #pragma unroll
        for (int off = 16; off; off >>= 1) es += __shfl_xor(es, off, 64);
        if (qq == 0) ws[SPUB + b * 16 + hf * 8 + hh] = es;
        __threadfence(); __syncthreads();
        if (tid == 0) { sig(&flg[F_S(b, hf)]); wt(&flg[F_S(b, 1 - hf)]); }
        __syncthreads(); __threadfence();
        const float S = es + vl(ws + SPUB + b * 16 + (1 - hf) * 8)[hh];
        const float inv = 1.f / S;
        #pragma unroll
        for (int i = 0; i < 4; ++i) scr[(4 * qq + i) * 17 + hh] = ev[i] * inv;
        __syncthreads();

        // xb-half (x from LDS, beta broadcast from LDS)
        float4 axb[8];
        #pragma unroll
        for (int h = 0; h < 8; ++h) axb[h] = {0.f, 0.f, 0.f, 0.f};
        #pragma unroll 4
        for (int j = 0; j < 16; ++j) {
            const int t = tc * 16 + j;
            const float4 xv = *(const float4*)(xS + t * 132 + 4 * q);
            #pragma unroll
            for (int h = 0; h < 8; ++h) {
                const float bb2 = scr[t * 17 + h];
                axb[h].x += bb2 * xv.x; axb[h].y += bb2 * xv.y;
                axb[h].z += bb2 * xv.z; axb[h].w += bb2 * xv.w;
            }
        }
        __syncthreads();                    // xS dead; reuse as partial buffer
        float* p = sm;                      // [8][1024]
        #pragma unroll
        for (int h = 0; h < 8; ++h) *(float4*)(p + tc * 1024 + h * 128 + 4 * q) = axb[h];
        __syncthreads();
        float4 own = {0.f, 0.f, 0.f, 0.f};
        {
            const int o = 4 * tid;
            #pragma unroll
            for (int g = 0; g < 8; ++g) {
                const float4 v = *(const float4*)(p + g * 1024 + o);
                own.x += v.x; own.y += v.y; own.z += v.z; own.w += v.w;
            }
        }
        if (hf == 0) {
            *(float4*)(ws + XBP0 + b * 1024 + 4 * tid) = own;
            __threadfence(); __syncthreads();
            if (tid == 0) sig(&flg[F_XB0(b)]);
        } else {
            if (tid == 0) wt(&flg[F_XB0(b)]);
            __syncthreads(); __threadfence();
            const float4 v0 = *(const float4*)(vl(ws + XBP0 + b * 1024) + 4 * tid);
            own.x += v0.x; own.y += v0.y; own.z += v0.z; own.w += v0.w;
            *(float4*)(ws + XBF + b * 1024 + 4 * tid) = own;
            __threadfence(); __syncthreads();
            if (tid == 0) sig(&flg[F_XBF(b)]);
        }
        return;

    } else if (id < 160) {
        // ---------------- Kw (he-chunk c) ----------------
        const int c = id - 128;
        float* wkT = sm;                     // [32][132] transposed slice
        float* swp = sm + 4224;
        const int e5 = tid & 31, bg = tid >> 5;
        #pragma unroll
        for (int i = 0; i < 4; ++i) {
            const int fi = tid + 256 * i;    // 1024 float4
            const int k = fi >> 3, cc = fi & 7;
            const float4 v = *(const float4*)(Wk + (size_t)k * 1024 + 32 * c + 4 * cc);
            wkT[(4*cc+0)*132 + k] = v.x; wkT[(4*cc+1)*132 + k] = v.y;
            wkT[(4*cc+2)*132 + k] = v.z; wkT[(4*cc+3)*132 + k] = v.w;
        }
        if (tid < 64) {                      // Sw
            const float4 wv = *(const float4*)(Wsv + 4 * tid);
            float s = wv.x + wv.y + wv.z + wv.w;
            #pragma unroll
            for (int off = 32; off; off >>= 1) s += __shfl_xor(s, off, 64);
            if (tid == 0) *swp = s;
        }
        __syncthreads();
        float4 wk4[32];
        #pragma unroll
        for (int k4 = 0; k4 < 32; ++k4) wk4[k4] = *(const float4*)(wkT + e5 * 132 + 4 * k4);
        const float swbk = (*swp) * bk[32 * c + e5];
        if (tid < 64) wt(&flg[F_XWF(tid)]);
        __syncthreads(); __threadfence();
        #pragma unroll
        for (int bb = 0; bb < 8; ++bb) {
            const int b = bg * 8 + bb;
            const float* xwp = vl(ws + XWF + b * 128);
            float4 a4 = {0.f, 0.f, 0.f, 0.f};
            #pragma unroll
            for (int k4 = 0; k4 < 32; ++k4) {
                const float4 xv = *(const float4*)(xwp + 4 * k4);
                a4.x += wk4[k4].x*xv.x; a4.y += wk4[k4].y*xv.y;
                a4.z += wk4[k4].z*xv.z; a4.w += wk4[k4].w*xv.w;
            }
            ws[KWQ + b * 1024 + 32 * c + e5] = a4.x + a4.y + a4.z + a4.w + swbk;
        }
        __threadfence(); __syncthreads();
        if (tid == 0) sig(&flg[F_KW(c)]);
        return;

    } else if (id < 192) {
        // ---------------- wqk (h, d-quarter) ----------------
        const int g = id - 160, h = g >> 2, dq = g & 3;
        float* wqS = sm;                     // [32][132]
        const int d5 = tid & 31, bg = tid >> 5;
        #pragma unroll
        for (int i = 0; i < 4; ++i) {
            const int fi = tid + 256 * i;
            const int d = fi >> 5, ec = fi & 31;
            *(float4*)(wqS + d * 132 + 4 * ec) =
                *(const float4*)(Wq + (size_t)(32 * dq + d) * 1024 + 128 * h + 4 * ec);
        }
        __syncthreads();
        float4 wq4[32];
        #pragma unroll
        for (int e4 = 0; e4 < 32; ++e4) wq4[e4] = *(const float4*)(wqS + d5 * 132 + 4 * e4);
        if (tid < 4) wt(&flg[F_KW(4 * h + tid)]);
        __syncthreads(); __threadfence();
        #pragma unroll
        for (int bb = 0; bb < 8; ++bb) {
            const int b = bg * 8 + bb;
            const float* kwp = vl(ws + KWQ + (size_t)b * 1024 + 128 * h);
            float4 a4 = {0.f, 0.f, 0.f, 0.f};
            #pragma unroll
            for (int e4 = 0; e4 < 32; ++e4) {
                const float4 kv = *(const float4*)(kwp + 4 * e4);
                a4.x += wq4[e4].x*kv.x; a4.y += wq4[e4].y*kv.y;
                a4.z += wq4[e4].z*kv.z; a4.w += wq4[e4].w*kv.w;
            }
            ws[WQKQ + b * 1024 + h * 128 + 32 * dq + d5] = (a4.x + a4.y + a4.z + a4.w) * SCALE;
        }
        __threadfence(); __syncthreads();
        if (tid == 0) sig(&flg[F_WQ(g)]);
        return;

    } else if (id < 224) {
        // ---------------- res (he-chunk c) ----------------
        const int c = id - 192, h = c >> 2;
        float* wvT = sm;                     // [32][132]
        const int e5 = tid & 31, bg = tid >> 5;
        #pragma unroll
        for (int i = 0; i < 4; ++i) {
            const int fi = tid + 256 * i;
            const int k = fi >> 3, cc = fi & 7;
            const float4 v = *(const float4*)(Wv + (size_t)k * 1024 + 32 * c + 4 * cc);
            wvT[(4*cc+0)*132 + k] = v.x; wvT[(4*cc+1)*132 + k] = v.y;
            wvT[(4*cc+2)*132 + k] = v.z; wvT[(4*cc+3)*132 + k] = v.w;
        }
        __syncthreads();
        float4 wv4[32];
        #pragma unroll
        for (int k4 = 0; k4 < 32; ++k4) wv4[k4] = *(const float4*)(wvT + e5 * 132 + 4 * k4);
        const float bvv = bv[32 * c + e5];
        if (tid < 64) wt(&flg[F_XBF(tid)]);
        __syncthreads(); __threadfence();
        #pragma unroll
        for (int bb = 0; bb < 8; ++bb) {
            const int b = bg * 8 + bb;
            const float* xbp = vl(ws + XBF + (size_t)b * 1024 + h * 128);
            float4 a4 = {0.f, 0.f, 0.f, 0.f};
            #pragma unroll
            for (int k4 = 0; k4 < 32; ++k4) {
                const float4 xv = *(const float4*)(xbp + 4 * k4);
                a4.x += wv4[k4].x*xv.x; a4.y += wv4[k4].y*xv.y;
                a4.z += wv4[k4].z*xv.z; a4.w += wv4[k4].w*xv.w;
            }
            ws[RESQ + b * 1024 + 32 * c + e5] = a4.x + a4.y + a4.z + a4.w + bvv;
        }
        __threadfence(); __syncthreads();
        if (tid == 0) sig(&flg[F_RS(c)]);
        return;

    } else {
        // ---------------- out (he-chunk c), atomicAdd ----------------
        const int c = id - 224;
        float* woT = sm;                     // [128][36]
        const int d7 = tid & 127, bg2 = tid >> 7;
        #pragma unroll
        for (int i = 0; i < 4; ++i) {
            const int fi = tid + 256 * i;
            const int he = fi >> 5, dc = fi & 31;
            const float4 v = *(const float4*)(Wo + (size_t)(32 * c + he) * 128 + 4 * dc);
            woT[(4*dc+0)*36 + he] = v.x; woT[(4*dc+1)*36 + he] = v.y;
            woT[(4*dc+2)*36 + he] = v.z; woT[(4*dc+3)*36 + he] = v.w;
        }
        __syncthreads();
        float4 wo4[8];
        #pragma unroll
        for (int m4 = 0; m4 < 8; ++m4) wo4[m4] = *(const float4*)(woT + d7 * 36 + 4 * m4);
        const float boa = (c == 0) ? bov[d7] : 0.f;
        if (tid == 0) wt(&flg[F_RS(c)]);
        __syncthreads(); __threadfence();
        #pragma unroll 4
        for (int bb = 0; bb < 32; ++bb) {
            const int b = bg2 * 32 + bb;
            const float* rp = vl(ws + RESQ + (size_t)b * 1024 + 32 * c);
            float4 a4 = {0.f, 0.f, 0.f, 0.f};
            #pragma unroll
            for (int m4 = 0; m4 < 8; ++m4) {
                const float4 rv = *(const float4*)(rp + 4 * m4);
                a4.x += wo4[m4].x*rv.x; a4.y += wo4[m4].y*rv.y;
                a4.z += wo4[m4].z*rv.z; a4.w += wo4[m4].w*rv.w;
            }
            atomicAdd(&out[(size_t)b * 128 + d7], a4.x + a4.y + a4.z + a4.w + boa);
        }
        return;
    }
}

extern "C" void kernel_launch(void* const* d_in, const int* in_sizes, int n_in,
                              void* d_out, int out_size, void* d_ws, size_t ws_size,
                              hipStream_t stream) {
    const float* x  = (const float*)d_in[0];
    const float* Wq = (const float*)d_in[1];
    // d_in[2] = bq  — softmax shift-invariant, unused
    const float* Wk = (const float*)d_in[3];
    const float* bk = (const float*)d_in[4];
    const float* Wv = (const float*)d_in[5];
    const float* bv = (const float*)d_in[6];
    const float* Ws = (const float*)d_in[7];
    // d_in[8] = bs  — softmax shift-invariant, unused
    const float* Wo = (const float*)d_in[9];
    const float* bo = (const float*)d_in[10];
    float* out = (float*)d_out;
    float* ws  = (float*)d_ws;

    hipMemsetAsync(out, 0, (size_t)out_size * sizeof(float), stream);
    ta_pipe<<<dim3(256), dim3(256), 0, stream>>>(x, Wq, Wk, bk, Wv, bv, Ws, Wo, bo, ws, out);
}

// Round 10
// 112.086 us; speedup vs baseline: 3.5106x; 3.5106x over previous
//
#include <hip/hip_runtime.h>
#include <hip/hip_bf16.h>

// B=64, T=256, D=128, H=8, E=128, H*E=1024.
// Algebra (verified R1-R9): with xw[b]=Ws^T x[b], Sw=sum(Ws):
//   Kw[b,e;h]  = xw[b] @ Wk[:,h*128+e] + Sw*bk
//   wqk[b,h,d] = SCALE * sum_e Wq[d,h*128+e]*Kw          (bq, bs drop)
//   beta[b,h,t]= softmax_t( x[b,t] . wqk[b,h] )
//   xb[b,h,d]  = sum_t beta*x[b,t,d]
//   res[b,e;h] = xb[b,h] @ Wv[:,h*128+e] + bv
//   out[b,d]   = res[b] @ Wo[:,d] + bo
//
// R10: grid (64,8) x 256, block=(b,h). NO register-resident x (R8's rx[32]
// = 128 VGPR caused spill/occupancy collapse at VGPR_Count=124): x is read
// from global 3x (phases A/D/E) with coalesced float4 streams; with linear
// block ids, id%8=b%8 -> all 8 h-blocks of b share one XCD whose L2 holds
// x[b]+all weights (3 MB < 4 MB), so re-reads are L2-hits. Max 16 live
// float4/thread -> ~100 VGPR -> 2+ blocks/CU truly resident (512 independent
// chains hide latency). Single node; R8's flag handshake for the h-reduction.

#define SCALE 0.08838834764831845f
#define MAGIC 0x13579BDFu
#define BAR() __asm__ volatile("s_waitcnt lgkmcnt(0)\n\ts_barrier" ::: "memory")

__global__ __launch_bounds__(256, 2)
void ta_one(const float* __restrict__ x,  const float* __restrict__ Wq,
            const float* __restrict__ Wk, const float* __restrict__ bk,
            const float* __restrict__ Wv, const float* __restrict__ bv,
            const float* __restrict__ Wsv,
            const float* __restrict__ Wo, const float* __restrict__ bov,
            float* __restrict__ ws, float* __restrict__ out)
{
    __shared__ __align__(16) float buf[2056];   // [8][257] row-dot / [8][128] col partials
    __shared__ __align__(16) float wsS[256];
    __shared__ __align__(16) float xwS[128];
    __shared__ __align__(16) float kwS[128];
    __shared__ __align__(16) float wqkS[128];   // pre-scaled
    __shared__ __align__(16) float betaS[256];
    __shared__ __align__(16) float xbS[128];
    __shared__ __align__(16) float resS[128];
    __shared__ float smx[4], sms[4];
    __shared__ float swS;

    const int tid = threadIdx.x;
    const int b = blockIdx.x, h = blockIdx.y;
    const int w = tid >> 6, l = tid & 63;
    const int q5 = tid & 31, tc = tid >> 5;   // col-streams: lane=16B of 128-dim, 8 chunks
    const int c8 = tid & 7,  r8 = tid >> 3;   // row-dots: chunk c8 of 4x16B, row-set r8
    const float* xp0 = x + (size_t)b * 32768;

    const float bkv = bk[h * 128 + (tid & 127)];
    const float bvv = bv[h * 128 + (tid & 127)];
    if (tid < 64) *(float4*)(wsS + 4 * tid) = *(const float4*)(Wsv + 4 * tid);
    BAR();

    // ---------- A: xw[d] = sum_t Ws[t]*x[t,d]  (x pass 1, coalesced) ----------
    {
        float4 acc = {0.f, 0.f, 0.f, 0.f};
        const float4* xp = (const float4*)(xp0 + (size_t)(tc * 32) * 128) + q5;
        #pragma unroll 8
        for (int j = 0; j < 32; ++j) {
            const float4 v = xp[(size_t)j * 32];
            const float s = wsS[tc * 32 + j];
            acc.x += s * v.x; acc.y += s * v.y; acc.z += s * v.z; acc.w += s * v.w;
        }
        *(float4*)(buf + tc * 128 + 4 * q5) = acc;
    }
    BAR();
    if (tid < 128) {
        float v = 0.f;
        #pragma unroll
        for (int g = 0; g < 8; ++g) v += buf[g * 128 + tid];
        xwS[tid] = v;
    } else if (tid < 192) {                    // Sw (one wave)
        float v = wsS[l] + wsS[l + 64] + wsS[l + 128] + wsS[l + 192];
        #pragma unroll
        for (int off = 32; off; off >>= 1) v += __shfl_xor(v, off, 64);
        if (l == 0) swS = v;
    }
    BAR();

    // ---------- B: Kw[e] = xw . Wk[:, h*128+e] + Sw*bk ----------
    {
        float4 acc = {0.f, 0.f, 0.f, 0.f};
        const float4* wp = (const float4*)(Wk + (size_t)(tc * 16) * 1024 + h * 128) + q5;
        #pragma unroll
        for (int j = 0; j < 16; ++j) {
            const float4 wv = wp[(size_t)j * 256];
            const float xv = xwS[tc * 16 + j];
            acc.x += xv * wv.x; acc.y += xv * wv.y;
            acc.z += xv * wv.z; acc.w += xv * wv.w;
        }
        *(float4*)(buf + tc * 128 + 4 * q5) = acc;
    }
    BAR();
    if (tid < 128) {
        float v = swS * bkv;
        #pragma unroll
        for (int g = 0; g < 8; ++g) v += buf[g * 128 + tid];
        kwS[tid] = v;
    }
    BAR();

    // ---------- C: wqk[d] = Wq[d, h*128..] . kw  (row-dot) ----------
    {
        #pragma unroll
        for (int rr = 0; rr < 4; ++rr) {
            const int d = 32 * rr + r8;
            const float* base = Wq + (size_t)d * 1024 + h * 128;
            float a = 0.f;
            #pragma unroll
            for (int m = 0; m < 4; ++m) {
                const int j4 = c8 + 8 * m;
                const float4 wv = *(const float4*)(base + 4 * j4);
                const float4 kv = *(const float4*)(kwS + 4 * j4);
                a += wv.x * kv.x + wv.y * kv.y + wv.z * kv.z + wv.w * kv.w;
            }
            buf[c8 * 257 + d] = a;
        }
    }
    BAR();
    if (tid < 128) {
        float v = 0.f;
        #pragma unroll
        for (int g = 0; g < 8; ++g) v += buf[g * 257 + tid];
        wqkS[tid] = v * SCALE;
    }
    BAR();

    // ---------- D: score[t] = x[t] . wqk  (x pass 2, row-dot) ----------
    {
        #pragma unroll
        for (int rr = 0; rr < 8; ++rr) {
            const int t = 32 * rr + r8;
            const float* base = xp0 + (size_t)t * 128;
            float a = 0.f;
            #pragma unroll
            for (int m = 0; m < 4; ++m) {
                const int j4 = c8 + 8 * m;
                const float4 xv = *(const float4*)(base + 4 * j4);
                const float4 qv = *(const float4*)(wqkS + 4 * j4);
                a += xv.x * qv.x + xv.y * qv.y + xv.z * qv.z + xv.w * qv.w;
            }
            buf[c8 * 257 + t] = a;
        }
    }
    BAR();

    // ---------- softmax over t (thread = t) ----------
    {
        float v = 0.f;
        #pragma unroll
        for (int g = 0; g < 8; ++g) v += buf[g * 257 + tid];
        float m = v;
        #pragma unroll
        for (int off = 32; off; off >>= 1) m = fmaxf(m, __shfl_xor(m, off, 64));
        if (l == 0) smx[w] = m;
        BAR();
        const float M = fmaxf(fmaxf(smx[0], smx[1]), fmaxf(smx[2], smx[3]));
        const float e = __expf(v - M);
        float ssum = e;
        #pragma unroll
        for (int off = 32; off; off >>= 1) ssum += __shfl_xor(ssum, off, 64);
        if (l == 0) sms[w] = ssum;
        BAR();
        betaS[tid] = e / (sms[0] + sms[1] + sms[2] + sms[3]);
    }
    BAR();

    // ---------- E: xb[d] = sum_t beta[t]*x[t,d]  (x pass 3, coalesced) --------
    {
        float4 acc = {0.f, 0.f, 0.f, 0.f};
        const float4* xp = (const float4*)(xp0 + (size_t)(tc * 32) * 128) + q5;
        #pragma unroll 8
        for (int j = 0; j < 32; ++j) {
            const float4 v = xp[(size_t)j * 32];
            const float bb = betaS[tc * 32 + j];
            acc.x += bb * v.x; acc.y += bb * v.y; acc.z += bb * v.z; acc.w += bb * v.w;
        }
        *(float4*)(buf + tc * 128 + 4 * q5) = acc;
    }
    BAR();
    if (tid < 128) {
        float v = 0.f;
        #pragma unroll
        for (int g = 0; g < 8; ++g) v += buf[g * 128 + tid];
        xbS[tid] = v;
    }
    BAR();

    // ---------- F: res[e] = xb . Wv[:, h*128+e] + bv ----------
    {
        float4 acc = {0.f, 0.f, 0.f, 0.f};
        const float4* wp = (const float4*)(Wv + (size_t)(tc * 16) * 1024 + h * 128) + q5;
        #pragma unroll
        for (int j = 0; j < 16; ++j) {
            const float4 wv = wp[(size_t)j * 256];
            const float xv = xbS[tc * 16 + j];
            acc.x += xv * wv.x; acc.y += xv * wv.y;
            acc.z += xv * wv.z; acc.w += xv * wv.w;
        }
        *(float4*)(buf + tc * 128 + 4 * q5) = acc;
    }
    BAR();
    if (tid < 128) {
        float v = bvv;
        #pragma unroll
        for (int g = 0; g < 8; ++g) v += buf[g * 128 + tid];
        resS[tid] = v;
    }
    BAR();

    // ---------- G: out-partial[d] = sum_e res[e]*Wo[h*128+e, d] ----------
    {
        float4 acc = {0.f, 0.f, 0.f, 0.f};
        const float4* wp = (const float4*)(Wo + (size_t)(h * 128 + tc * 16) * 128) + q5;
        #pragma unroll
        for (int j = 0; j < 16; ++j) {
            const float4 wv = wp[(size_t)j * 32];
            const float rv = resS[tc * 16 + j];
            acc.x += rv * wv.x; acc.y += rv * wv.y;
            acc.z += rv * wv.z; acc.w += rv * wv.w;
        }
        *(float4*)(buf + tc * 128 + 4 * q5) = acc;
    }
    __syncthreads();   // full barrier: global visibility ordering next

    // ---------- cross-block reduce over h (ws poisoned 0xAA each call) --------
    float* part = ws;                               // [64*8*128]
    unsigned* flags = (unsigned*)(ws + 65536);      // [512]
    if (h < 7) {
        if (tid < 128) {
            float v = 0.f;
            #pragma unroll
            for (int g = 0; g < 8; ++g) v += buf[g * 128 + tid];
            part[(size_t)(b * 8 + h) * 128 + tid] = v;
            __threadfence();
        }
        __syncthreads();
        if (tid == 0) atomicExch(&flags[b * 8 + h], MAGIC);
    } else {
        if (tid == 0) {
            #pragma unroll
            for (int i = 0; i < 7; ++i)
                while (atomicCAS(&flags[b * 8 + i], MAGIC, MAGIC) != MAGIC) {}
        }
        __syncthreads();
        if (tid < 128) {
            float v = bov[tid];
            #pragma unroll
            for (int g = 0; g < 8; ++g) v += buf[g * 128 + tid];
            #pragma unroll
            for (int i = 0; i < 7; ++i)
                v += atomicAdd(&part[(size_t)(b * 8 + i) * 128 + tid], 0.f);
            out[(size_t)b * 128 + tid] = v;
        }
    }
}

extern "C" void kernel_launch(void* const* d_in, const int* in_sizes, int n_in,
                              void* d_out, int out_size, void* d_ws, size_t ws_size,
                              hipStream_t stream) {
    const float* x  = (const float*)d_in[0];
    const float* Wq = (const float*)d_in[1];
    // d_in[2] = bq  — softmax shift-invariant, unused
    const float* Wk = (const float*)d_in[3];
    const float* bk = (const float*)d_in[4];
    const float* Wv = (const float*)d_in[5];
    const float* bv = (const float*)d_in[6];
    const float* Ws = (const float*)d_in[7];
    // d_in[8] = bs  — softmax shift-invariant, unused
    const float* Wo = (const float*)d_in[9];
    const float* bo = (const float*)d_in[10];
    float* out = (float*)d_out;
    float* ws  = (float*)d_ws;

    ta_one<<<dim3(64, 8), dim3(256), 0, stream>>>(x, Wq, Wk, bk, Wv, bv, Ws, Wo, bo, ws, out);
}